// Round 1
// baseline (1027.944 us; speedup 1.0000x reference)
//
#include <hip/hip_runtime.h>
#include <hip/hip_bf16.h>

// d = 256, 32 blocks of 8 on the diagonal are zero.
// out[N=500000, 256] = X[500000, 256] @ W[256, 256]
//
// Strategy: bf16 MFMA (16x16x32), memory-bound at ~1.02 GB HBM traffic.
// W is tiny (128 KB bf16) -> precompute in MFMA B-fragment layout in d_ws,
// read per-wave from L2. A (X) staged fp32->bf16 through LDS.

typedef __bf16 bf16x8 __attribute__((ext_vector_type(8)));
typedef __bf16 bf16x4 __attribute__((ext_vector_type(4)));
typedef float  f32x4  __attribute__((ext_vector_type(4)));

#define D 256
#define TILE_M 64
#define LDS_PITCH 264   // 256 + 8 bf16 pad: row stride 528 B -> bank step 4, 2-way only (free)

// ---------------- kernel 1: scatter w_est into dense fp32 W ----------------
__global__ void scatter_w(const float* __restrict__ w_est,
                          const int* __restrict__ rows,
                          const int* __restrict__ cols,
                          float* __restrict__ Wd, int nnz) {
    int i = blockIdx.x * blockDim.x + threadIdx.x;
    if (i < nnz) Wd[rows[i] * D + cols[i]] = w_est[i];
}

// ------- kernel 2: pack dense W into B-fragment layout, bf16 -------
// Fragment for MFMA f32_16x16x32_bf16, B operand: lane l holds
// B[k = 8*(l>>4) + j][n = l&15], j=0..7 (16 B contiguous per lane).
// Wf element index: ((s*16 + t)*64 + lane)*8 + j   (s = k-step 0..7, t = n-tile 0..15)
__global__ void pack_w(const float* __restrict__ Wd, __bf16* __restrict__ Wf) {
    int id   = blockIdx.x * 256 + threadIdx.x;   // 8192 threads total
    int lane = id & 63;
    int t    = (id >> 6) & 15;
    int s    = id >> 10;
    int n    = t * 16 + (lane & 15);
    int k0   = s * 32 + (lane >> 4) * 8;
    bf16x8 h;
#pragma unroll
    for (int j = 0; j < 8; ++j) h[j] = (__bf16)Wd[(k0 + j) * D + n];
    *(bf16x8*)(Wf + (size_t)id * 8) = h;
}

// ---------------- kernel 3: the GEMM ----------------
// Block: 256 threads = 4 waves. Each block: 64 rows x 256 cols.
// Wave w: rows [16w, 16w+16), all 16 n-tiles. acc = 16 tiles x 4 f32 = 64 VGPRs.
__global__ __launch_bounds__(256) void dag_gemm(const float* __restrict__ X,
                                                const __bf16* __restrict__ Wf,
                                                float* __restrict__ out, int M) {
    __shared__ __bf16 lds[TILE_M * LDS_PITCH];   // 33792 B

    const int tid  = threadIdx.x;
    const int wave = tid >> 6;
    const int lane = tid & 63;
    const long row0 = (long)blockIdx.x * TILE_M;

    // ---- stage A tile: 64 rows x 256 fp32 -> bf16 LDS, fully coalesced ----
    // float4 granularity: 4096 float4 / 256 threads = 16 iters, 4 KB contiguous per iter.
#pragma unroll
    for (int i = 0; i < 16; ++i) {
        int idx = i * 256 + tid;          // float4 index within tile
        int r   = idx >> 6;               // 0..63
        int c4  = idx & 63;               // float4 column
        long gr = row0 + r;
        if (gr >= M) gr = 0;              // tail: load row 0, stores are masked
        f32x4 v = *(const f32x4*)(X + gr * D + c4 * 4);
        bf16x4 h;
#pragma unroll
        for (int j = 0; j < 4; ++j) h[j] = (__bf16)v[j];
        *(bf16x4*)(&lds[r * LDS_PITCH + c4 * 4]) = h;   // 8 B, conflict-free
    }

    f32x4 acc[16];
#pragma unroll
    for (int t = 0; t < 16; ++t) acc[t] = 0.0f;

    // A-fragment source: lane l reads A[m = l&15][k = 8*(l>>4) + j]
    const __bf16* a_base = &lds[(wave * 16 + (lane & 15)) * LDS_PITCH + (lane >> 4) * 8];
    const bf16x8* b_base = (const bf16x8*)Wf + lane;

    __syncthreads();

    // ---- K loop: 8 steps of K=32, 16 MFMAs (one per n-tile) each ----
    for (int s = 0; s < 8; ++s) {
        bf16x8 a = *(const bf16x8*)(a_base + s * 32);   // ds_read_b128
        const bf16x8* bp = b_base + s * 1024;           // (s*16+t)*64 + lane
#pragma unroll
        for (int t = 0; t < 16; ++t) {
            bf16x8 b = bp[t * 64];                      // global dwordx4, L2-hot
            acc[t] = __builtin_amdgcn_mfma_f32_16x16x32_bf16(a, b, acc[t], 0, 0, 0);
        }
    }

    // ---- epilogue: C/D layout col = lane&15, row = (lane>>4)*4 + reg ----
    const int col   = lane & 15;
    const int rbase = wave * 16 + (lane >> 4) * 4;
#pragma unroll
    for (int t = 0; t < 16; ++t) {
#pragma unroll
        for (int r = 0; r < 4; ++r) {
            long orow = row0 + rbase + r;
            if (orow < M) out[orow * D + t * 16 + col] = acc[t][r];
        }
    }
}

extern "C" void kernel_launch(void* const* d_in, const int* in_sizes, int n_in,
                              void* d_out, int out_size, void* d_ws, size_t ws_size,
                              hipStream_t stream) {
    const float* X     = (const float*)d_in[0];
    const float* w_est = (const float*)d_in[1];
    const int*   rows  = (const int*)d_in[2];
    const int*   cols  = (const int*)d_in[3];
    float* out = (float*)d_out;

    const int nnz = in_sizes[1];
    const int M   = in_sizes[0] / D;

    float*  Wd = (float*)d_ws;                          // 256 KB dense fp32 W
    __bf16* Wf = (__bf16*)((char*)d_ws + 256 * 1024);   // 128 KB fragment-layout bf16 W

    hipMemsetAsync(Wd, 0, D * D * sizeof(float), stream);
    scatter_w<<<(nnz + 255) / 256, 256, 0, stream>>>(w_est, rows, cols, Wd, nnz);
    pack_w<<<32, 256, 0, stream>>>(Wd, Wf);

    int mblocks = (M + TILE_M - 1) / TILE_M;
    dag_gemm<<<mblocks, 256, 0, stream>>>(X, Wf, out, M);
}